// Round 1
// 1125.498 us; speedup vs baseline: 1.4302x; 1.4302x over previous
//
#include <hip/hip_runtime.h>

// ---------------------------------------------------------------------------
// WindowAttention on MI355X (gfx950) — fused attention + split proj GEMM.
// B_=4096 windows, S=49 (7x7), D=384, H=6 heads, hd=64, Wn=64 masks.
//
// v2 restructure (latency/barrier-bound per rocprof: MfmaUtil 10.7, occ 23.8):
//   - proj GEMM split out (removes pacc[24]=96 regs + 8 barriers/head)
//   - in-register softmax via __shfl_xor (removes Sc 16.6KB + 2 barriers/head)
//   - LDS 65024 -> 52224 B => 3 blocks/CU, __launch_bounds__(256,3)
//   - QKV weight staging double-buffered Ws<->Pb: 14 barriers/head vs ~35
//   - A-fragments (x as bf16) hoisted: converted once per block, not per head
//   - V stored transposed: PV B-frags = 8 ds_read_b128 (was 64 ds_read_u16)
// Workspace: ~152 MB (weights + bias/mask table + bf16 O tensor).
// ---------------------------------------------------------------------------

typedef __attribute__((ext_vector_type(8))) short bfx8;  // 8 x bf16
typedef __attribute__((ext_vector_type(4))) float fx4;   // MFMA accumulator

typedef const __attribute__((address_space(1))) void* gptr_t;
typedef __attribute__((address_space(3))) void* lptr_t;

__device__ __forceinline__ short f2bf(float f) {
  union { float f; unsigned u; } v;
  v.f = f;
  unsigned r = v.u + 0x7fffu + ((v.u >> 16) & 1u);  // round-to-nearest-even
  return (short)(r >> 16);
}

// ------------------------------ prep kernels -------------------------------

// wt[n][k] = bf16(w[k][n]); w is K x N row-major.
__global__ __launch_bounds__(256) void convT_kernel(const float* __restrict__ w,
                                                    short* __restrict__ wt, int N, int K) {
  int i = blockIdx.x * 256 + threadIdx.x;
  if (i < N * K) {
    int n = i / K, k = i - n * K;
    wt[i] = f2bf(w[(size_t)k * N + n]);
  }
}

// bm[(w*6+h)*2401 + rc] = bias_table[rel_index[rc]*6 + h] + mask[w*2401 + rc]
__global__ __launch_bounds__(256) void bm_kernel(const float* __restrict__ mask,
                                                 const float* __restrict__ bias_table,
                                                 const int* __restrict__ rel_index,
                                                 float* __restrict__ bm) {
  int i = blockIdx.x * 256 + threadIdx.x;
  if (i < 64 * 6 * 2401) {
    int rc = i % 2401;
    int wh = i / 2401;
    int h = wh % 6, w = wh / 6;
    bm[i] = bias_table[rel_index[rc] * 6 + h] + mask[w * 2401 + rc];
  }
}

// ------------------------------ fused kernel -------------------------------
// One block (4 waves) per window. Per head:
//   QKV GEMM (dbuf staged weights) -> Qs/Ks/Vt -> QK^T -> in-reg softmax
//   -> P (LDS, wave-local rows) -> PV -> O (global bf16)
// LDS: Qs 9216 + Ks 9216 + Vt 9216 + Pb 12288 + Ws 12288 = 52,224 B
//   => 3 blocks/CU (156,672 <= 163,840)

__global__ __launch_bounds__(256, 3) void fused_attn_kernel(
    const float* __restrict__ x,        // [4096*49][384] fp32
    const short* __restrict__ wqkv_t,   // [1152][384] bf16 (n-major)
    const float* __restrict__ qkv_b,    // [1152]
    const float* __restrict__ bm,       // [64][6][49][49]
    short* __restrict__ O) {            // [4096*49][384] bf16
  __shared__ __align__(16) short Qs[64 * 72];
  __shared__ __align__(16) short Ks[64 * 72];
  __shared__ __align__(16) short Vt[64 * 72];  // transposed: Vt[e][row]
  __shared__ __align__(16) short Pb[6144];     // stage buf 1 / P (stride 72)
  __shared__ __align__(16) short Ws[6144];     // stage buf 0

  const int tid = threadIdx.x;
  const int lane = tid & 63, wid = tid >> 6;
  const int l15 = lane & 15, q4 = lane >> 4;
  const int b = blockIdx.x, w = b & 63;
  const float* xw = x + (size_t)b * 49 * 384;
  const float* bmp_base = bm + ((size_t)(w * 6)) * 2401;

  const fx4 zero = {0.f, 0.f, 0.f, 0.f};
  const int arow = wid * 16 + l15;     // A-operand row this lane reads
  const int crow = wid * 16 + q4 * 4;  // C-fragment base row this lane holds

  // stage one 192x32 weight tile (12,288 B) into dst
  auto stage = [&](short* dst, int h64s, int kts) {
#pragma unroll
    for (int r = 0; r < 3; ++r) {
      const int off = r * 4096 + tid * 16;
      const int srow = off >> 6;       // 0..191 (64 B per row)
      const int ce = (off & 63) >> 1;  // element within 32-elem chunk
      const int n = (srow >> 6) * 384 + h64s + (srow & 63);
      __builtin_amdgcn_global_load_lds(
          (gptr_t)(wqkv_t + (size_t)n * 384 + kts * 32 + ce),
          (lptr_t)((char*)dst + off), 16, 0, 0);
    }
  };

  // ---- hoist A: x rows as bf16 fragments for all 12 k-tiles (48 VGPR) ----
  bfx8 af_all[12];
#pragma unroll
  for (int kt = 0; kt < 12; ++kt) {
    float4 a0 = {0.f, 0.f, 0.f, 0.f}, a1 = {0.f, 0.f, 0.f, 0.f};
    if (arow < 49) {
      const float4* ap = (const float4*)(xw + (size_t)arow * 384 + kt * 32 + q4 * 8);
      a0 = ap[0];
      a1 = ap[1];
    }
    bfx8 af;
    af[0] = f2bf(a0.x); af[1] = f2bf(a0.y); af[2] = f2bf(a0.z); af[3] = f2bf(a0.w);
    af[4] = f2bf(a1.x); af[5] = f2bf(a1.y); af[6] = f2bf(a1.z); af[7] = f2bf(a1.w);
    af_all[kt] = af;
  }

  stage(Ws, 0, 0);  // prologue: head 0, kt 0

  for (int h = 0; h < 6; ++h) {
    const int h64 = h * 64;
    __syncthreads();  // B1: stage(h,0) visible; all waves done with prev attn

    // ---------------- QKV GEMM for head h: [64x384] @ [192x384]^T ----------
    fx4 qacc[12];
#pragma unroll
    for (int i = 0; i < 12; ++i) qacc[i] = zero;

#pragma unroll
    for (int kt = 0; kt < 12; ++kt) {
      short* sb = (kt & 1) ? Ws : Pb;        // buffer staged now (for kt+1)
      const short* rb = (kt & 1) ? Pb : Ws;  // buffer read now
      if (kt < 11) stage(sb, h64, kt + 1);   // loads in flight across MFMAs
      const bfx8 af = af_all[kt];
#pragma unroll
      for (int nt = 0; nt < 12; ++nt) {
        const bfx8 bf = *(const bfx8*)&rb[(nt * 16 + l15) * 32 + q4 * 8];
        qacc[nt] = __builtin_amdgcn_mfma_f32_16x16x32_bf16(af, bf, qacc[nt], 0, 0, 0);
      }
      __syncthreads();  // B2..B13
    }

    // epilogue: +bias, scale q, write Qs/Ks/Vt (bf16)
#pragma unroll
    for (int nt = 0; nt < 12; ++nt) {
      const int which = nt >> 2;          // 0=q 1=k 2=v
      const int e = (nt & 3) * 16 + l15;  // 0..63 within head
      const float bias = qkv_b[which * 384 + h64 + e];
      const float sc = (which == 0) ? 0.125f : 1.0f;
#pragma unroll
      for (int rr = 0; rr < 4; ++rr) {
        const int row = crow + rr;
        const short v = f2bf((qacc[nt][rr] + bias) * sc);
        if (which == 0)      Qs[row * 72 + e] = v;
        else if (which == 1) Ks[row * 72 + e] = v;
        else                 Vt[e * 72 + row] = v;  // transposed for PV b128
      }
    }
    __syncthreads();  // B14: Qs/Ks/Vt visible

    // next head's first weight tile: issued here, drains at next B1 (overlaps
    // with the whole attention phase). Ws is dead until then.
    if (h < 5) stage(Ws, h64 + 64, 0);

    // bias+mask prefetch (independent of QK^T -> issues early)
    const float* bmp = bmp_base + (size_t)h * 2401;
    float bmv[4][4];
#pragma unroll
    for (int nt = 0; nt < 4; ++nt) {
      const int c = nt * 16 + l15;
#pragma unroll
      for (int rr = 0; rr < 4; ++rr) {
        const int r = crow + rr;
        bmv[nt][rr] = (r < 49 && c < 49) ? bmp[r * 49 + c] : -1e30f;
      }
    }

    // ---------------- S = Q @ K^T (64x64, rows wid*16..) -------------------
    fx4 sacc[4];
#pragma unroll
    for (int i = 0; i < 4; ++i) sacc[i] = zero;
#pragma unroll
    for (int ks = 0; ks < 2; ++ks) {
      const bfx8 aq = *(const bfx8*)&Qs[arow * 72 + ks * 32 + q4 * 8];
#pragma unroll
      for (int nt = 0; nt < 4; ++nt) {
        const bfx8 bk = *(const bfx8*)&Ks[(nt * 16 + l15) * 72 + ks * 32 + q4 * 8];
        sacc[nt] = __builtin_amdgcn_mfma_f32_16x16x32_bf16(aq, bk, sacc[nt], 0, 0, 0);
      }
    }

    // ---------------- in-register softmax ----------------------------------
    // Row r=crow+rr lives across the 16 lanes sharing q4 (cols nt*16+l15).
    // shfl_xor 1/2/4/8 reduces within that group. Pad cols get -1e30 ->
    // exp underflows to exact 0; pad rows produce garbage but are discarded
    // at the O-store (all values stay finite: Q/K pad rows are bias-only).
    float p[4][4], mx[4], sm[4];
#pragma unroll
    for (int rr = 0; rr < 4; ++rr) mx[rr] = -1e30f;
#pragma unroll
    for (int nt = 0; nt < 4; ++nt)
#pragma unroll
      for (int rr = 0; rr < 4; ++rr) {
        p[nt][rr] = sacc[nt][rr] + bmv[nt][rr];
        mx[rr] = fmaxf(mx[rr], p[nt][rr]);
      }
#pragma unroll
    for (int rr = 0; rr < 4; ++rr) {
      mx[rr] = fmaxf(mx[rr], __shfl_xor(mx[rr], 1));
      mx[rr] = fmaxf(mx[rr], __shfl_xor(mx[rr], 2));
      mx[rr] = fmaxf(mx[rr], __shfl_xor(mx[rr], 4));
      mx[rr] = fmaxf(mx[rr], __shfl_xor(mx[rr], 8));
      sm[rr] = 0.f;
    }
#pragma unroll
    for (int nt = 0; nt < 4; ++nt)
#pragma unroll
      for (int rr = 0; rr < 4; ++rr) {
        const float e = __expf(p[nt][rr] - mx[rr]);
        p[nt][rr] = e;
        sm[rr] += e;
      }
#pragma unroll
    for (int rr = 0; rr < 4; ++rr) {
      sm[rr] += __shfl_xor(sm[rr], 1);
      sm[rr] += __shfl_xor(sm[rr], 2);
      sm[rr] += __shfl_xor(sm[rr], 4);
      sm[rr] += __shfl_xor(sm[rr], 8);
      sm[rr] = 1.f / sm[rr];
    }
    // P -> Pb (bf16, stride 72). Wave writes exactly its own 16x64 strip,
    // and PV reads only that strip -> no barrier needed.
#pragma unroll
    for (int nt = 0; nt < 4; ++nt)
#pragma unroll
      for (int rr = 0; rr < 4; ++rr)
        Pb[(crow + rr) * 72 + nt * 16 + l15] = f2bf(p[nt][rr] * sm[rr]);

    // ---------------- O_h = P @ V (64x64) -> global bf16 -------------------
    fx4 oacc[4];
#pragma unroll
    for (int i = 0; i < 4; ++i) oacc[i] = zero;
#pragma unroll
    for (int ks = 0; ks < 2; ++ks) {
      const bfx8 ap = *(const bfx8*)&Pb[arow * 72 + ks * 32 + q4 * 8];
#pragma unroll
      for (int nt = 0; nt < 4; ++nt) {
        const bfx8 bv = *(const bfx8*)&Vt[(nt * 16 + l15) * 72 + ks * 32 + q4 * 8];
        oacc[nt] = __builtin_amdgcn_mfma_f32_16x16x32_bf16(ap, bv, oacc[nt], 0, 0, 0);
      }
    }
#pragma unroll
    for (int nt = 0; nt < 4; ++nt)
#pragma unroll
      for (int rr = 0; rr < 4; ++rr) {
        const int r = crow + rr;
        if (r < 49)
          O[((size_t)b * 49 + r) * 384 + h64 + nt * 16 + l15] = f2bf(oacc[nt][rr]);
      }
  }  // heads
}

// ------------------------------ proj kernel --------------------------------
// out = O @ proj_w + proj_b.  M=200704 (=128*1568), N=384 (=128*3), K=384
// (=32*12): exact tiling, no tails. m97-style 128x128 tile, 4 waves (2x2),
// 64x64 per wave, global_load_lds(16B) staging, 16 MFMA / wave / K-step.

__global__ __launch_bounds__(256) void proj_kernel(
    const short* __restrict__ O,        // [200704][384] bf16
    const short* __restrict__ wproj_t,  // [384][384] bf16 (n-major)
    const float* __restrict__ proj_b,   // [384]
    float* __restrict__ out) {          // [200704][384] fp32
  __shared__ __align__(16) short As[128 * 32];
  __shared__ __align__(16) short Bs[128 * 32];

  const int tid = threadIdx.x;
  const int lane = tid & 63, wid = tid >> 6;
  const int l15 = lane & 15, q4 = lane >> 4;
  const int tn = blockIdx.x % 3, tm = blockIdx.x / 3;
  const int wr = wid >> 1, wc = wid & 1;  // 2x2 wave grid

  const short* Abase = O + (size_t)tm * 128 * 384;
  const short* Bbase = wproj_t + (size_t)tn * 128 * 384;

  fx4 acc[4][4];
#pragma unroll
  for (int i = 0; i < 4; ++i)
#pragma unroll
    for (int j = 0; j < 4; ++j) acc[i][j] = (fx4){0.f, 0.f, 0.f, 0.f};

  for (int kt = 0; kt < 12; ++kt) {
#pragma unroll
    for (int g = 0; g < 2; ++g) {
      const int off = g * 4096 + tid * 16;
      const int row = off >> 6;
      const int ce = (off & 63) >> 1;
      __builtin_amdgcn_global_load_lds(
          (gptr_t)(Abase + (size_t)row * 384 + kt * 32 + ce),
          (lptr_t)((char*)As + off), 16, 0, 0);
      __builtin_amdgcn_global_load_lds(
          (gptr_t)(Bbase + (size_t)row * 384 + kt * 32 + ce),
          (lptr_t)((char*)Bs + off), 16, 0, 0);
    }
    __syncthreads();
    bfx8 a[4], bf[4];
#pragma unroll
    for (int mi = 0; mi < 4; ++mi)
      a[mi] = *(const bfx8*)&As[(wr * 64 + mi * 16 + l15) * 32 + q4 * 8];
#pragma unroll
    for (int ni = 0; ni < 4; ++ni)
      bf[ni] = *(const bfx8*)&Bs[(wc * 64 + ni * 16 + l15) * 32 + q4 * 8];
#pragma unroll
    for (int mi = 0; mi < 4; ++mi)
#pragma unroll
      for (int ni = 0; ni < 4; ++ni)
        acc[mi][ni] = __builtin_amdgcn_mfma_f32_16x16x32_bf16(a[mi], bf[ni], acc[mi][ni], 0, 0, 0);
    __syncthreads();
  }

#pragma unroll
  for (int ni = 0; ni < 4; ++ni) {
    const int gn = tn * 128 + wc * 64 + ni * 16 + l15;
    const float bias = proj_b[gn];
#pragma unroll
    for (int mi = 0; mi < 4; ++mi) {
      const size_t gm = (size_t)tm * 128 + wr * 64 + mi * 16 + q4 * 4;
#pragma unroll
      for (int rr = 0; rr < 4; ++rr)
        out[(gm + rr) * 384 + gn] = acc[mi][ni][rr] + bias;
    }
  }
}

// ------------------------------- launcher ----------------------------------

extern "C" void kernel_launch(void* const* d_in, const int* in_sizes, int n_in,
                              void* d_out, int out_size, void* d_ws, size_t ws_size,
                              hipStream_t stream) {
  const float* x       = (const float*)d_in[0];
  const float* mask    = (const float*)d_in[1];
  const float* qkv_w   = (const float*)d_in[2];
  const float* qkv_b   = (const float*)d_in[3];
  const float* proj_w  = (const float*)d_in[4];
  const float* proj_b  = (const float*)d_in[5];
  const float* bias_t  = (const float*)d_in[6];
  const int*   rel_idx = (const int*)d_in[7];
  float* out = (float*)d_out;

  char* ws = (char*)d_ws;
  short* wqkv_t  = (short*)(ws);                       // 1152*384*2 =   884,736 B
  short* wproj_t = (short*)(ws + 884736);              //  384*384*2 =   294,912 B
  float* bmw     = (float*)(ws + 884736 + 294912);     // 64*6*49*49*4 = 3,687,936 B
  short* O_ws    = (short*)(ws + 884736 + 294912 + 3687936);
  // O_ws: 4096*49*384*2 = 154,140,672 B ; total workspace ~158 MB

  convT_kernel<<<1728, 256, 0, stream>>>(qkv_w, wqkv_t, 1152, 384);
  convT_kernel<<<576, 256, 0, stream>>>(proj_w, wproj_t, 384, 384);
  bm_kernel<<<3602, 256, 0, stream>>>(mask, bias_t, rel_idx, bmw);

  fused_attn_kernel<<<4096, 256, 0, stream>>>(x, wqkv_t, qkv_b, bmw, O_ws);
  proj_kernel<<<4704, 256, 0, stream>>>(O_ws, wproj_t, proj_b, out);
}